// Round 1
// baseline (923.043 us; speedup 1.0000x reference)
//
#include <hip/hip_runtime.h>
#include <stdint.h>
#include <stddef.h>

#define HEADS 24
#define HD    128
#define BB    2
#define SS    2304
#define DD    3072      // HEADS*HD
#define NN3   9216      // 3*DD
#define MM    4608      // BB*SS

typedef unsigned short ushort_t;
typedef __bf16 bf16x8 __attribute__((ext_vector_type(8)));
typedef float  f32x4  __attribute__((ext_vector_type(4)));

__device__ __forceinline__ unsigned short f2b(float f) {
  unsigned u = __float_as_uint(f);
  return (unsigned short)((u + 0x7fffu + ((u >> 16) & 1u)) >> 16);
}
__device__ __forceinline__ float b2f(unsigned short s) {
  return __uint_as_float(((unsigned)s) << 16);
}

// async global->LDS, 16B per lane. Pass the PER-LANE lds pointer (base + lane*16):
// correct under both "uniform base" and "firstlane" semantics, and keeps the
// fallback path correct.
__device__ __forceinline__ void gload_lds16(const void* g, void* l) {
#if __has_builtin(__builtin_amdgcn_global_load_lds)
  __builtin_amdgcn_global_load_lds(
      (const __attribute__((address_space(1))) unsigned int*)g,
      (__attribute__((address_space(3))) unsigned int*)l, 16, 0, 0);
#else
  *(uint4*)l = *(const uint4*)g;
#endif
}

// ---------------- kernel 1: f32 -> bf16 convert (8 elems/thread) --------------
__global__ __launch_bounds__(256) void cvt_bf16_kernel(
    const float* __restrict__ src, ushort_t* __restrict__ dst, int n8)
{
  int i = blockIdx.x * 256 + threadIdx.x;
  if (i >= n8) return;
  const float4* s = (const float4*)src + (size_t)i * 2;
  float4 a = s[0], b = s[1];
  union { ushort_t u[8]; uint4 v; } o;
  o.u[0] = f2b(a.x); o.u[1] = f2b(a.y); o.u[2] = f2b(a.z); o.u[3] = f2b(a.w);
  o.u[4] = f2b(b.x); o.u[5] = f2b(b.y); o.u[6] = f2b(b.z); o.u[7] = f2b(b.w);
  ((uint4*)dst)[i] = o.v;
}

// ---------------- kernel 2: QKV GEMM (m97 structure) --------------------------
// C[m][n] = A[m][:] . Bw[n][:] + bias[n], A=[4608][3072], Bw=[9216][3072] (B^T form)
#define BM 128
#define BN 128
#define BK 32
__global__ __launch_bounds__(256) void gemm_qkv_kernel(
    const ushort_t* __restrict__ A, const ushort_t* __restrict__ Bw,
    const float* __restrict__ bias, ushort_t* __restrict__ C)
{
  __shared__ ushort_t Al[BM * BK];   // [128][32] bf16, row-major (global_load_lds order)
  __shared__ ushort_t Bl[BN * BK];
  const int t = threadIdx.x;
  const int w = t >> 6, l = t & 63;
  const int quad = l >> 4, lq = l & 15;
  const int wm = (w >> 1) << 6, wn = (w & 1) << 6;
  const int m0 = blockIdx.y * BM, n0 = blockIdx.x * BN;

  f32x4 acc[4][4] = {};

  for (int kb = 0; kb < DD; kb += BK) {
    __syncthreads();
#pragma unroll
    for (int i = 0; i < 2; ++i) {
      int c = i * 256 + t;          // 0..511 chunks of 16B
      int r = c >> 2, sub = c & 3;  // row, 8-elem sub-chunk
      gload_lds16(A + (size_t)(m0 + r) * DD + kb + sub * 8, (char*)Al + (size_t)c * 16);
      gload_lds16(Bw + (size_t)(n0 + r) * DD + kb + sub * 8, (char*)Bl + (size_t)c * 16);
    }
    __syncthreads();
    bf16x8 af[4], bfr[4];
#pragma unroll
    for (int i = 0; i < 4; ++i)
      af[i] = *(const bf16x8*)((const char*)Al + ((wm + i * 16 + lq) * BK + quad * 8) * 2);
#pragma unroll
    for (int j = 0; j < 4; ++j)
      bfr[j] = *(const bf16x8*)((const char*)Bl + ((wn + j * 16 + lq) * BK + quad * 8) * 2);
#pragma unroll
    for (int i = 0; i < 4; ++i)
#pragma unroll
      for (int j = 0; j < 4; ++j)
        acc[i][j] = __builtin_amdgcn_mfma_f32_16x16x32_bf16(af[i], bfr[j], acc[i][j], 0, 0, 0);
  }
  // epilogue: + bias, cvt bf16. C/D layout: row = quad*4+r, col = lq
#pragma unroll
  for (int j = 0; j < 4; ++j) {
    int n = n0 + wn + j * 16 + lq;
    float bj = bias[n];
#pragma unroll
    for (int i = 0; i < 4; ++i) {
      int mb = m0 + wm + i * 16 + quad * 4;
#pragma unroll
      for (int r = 0; r < 4; ++r)
        C[(size_t)(mb + r) * NN3 + n] = f2b(acc[i][j][r] + bj);
    }
  }
}

// ---------------- kernel 3: RMSNorm + interleaved RoPE, in-place on q,k -------
// one wave per (b,s,h,which). lane l holds dims (2l, 2l+1) == rope pair l.
__global__ __launch_bounds__(256) void norm_rope_kernel(
    ushort_t* __restrict__ qkv, const float* __restrict__ wq,
    const float* __restrict__ wk, const float* __restrict__ cosb,
    const float* __restrict__ sinb, const int* __restrict__ tptr)
{
  const int T = *tptr;
  const int t = threadIdx.x, w = t >> 6, l = t & 63;
  int task = blockIdx.x * 4 + w;       // ((b*SS+s)*HEADS+h)*2+which
  int which = task & 1;
  int rest = task >> 1;
  int h = rest % HEADS;
  int sm = rest / HEADS;               // b*SS + s
  int s = sm % SS;
  size_t base = (size_t)sm * NN3 + which * DD + h * HD + 2 * l;
  unsigned pr = *(const unsigned*)(qkv + base);
  float x1 = b2f((unsigned short)(pr & 0xffffu));
  float x2 = b2f((unsigned short)(pr >> 16));
  float ss = x1 * x1 + x2 * x2;
#pragma unroll
  for (int m = 1; m < 64; m <<= 1) ss += __shfl_xor(ss, m, 64);
  float rr = rsqrtf(ss * (1.0f / 128.0f) + 1e-6f);
  const float* wn = which ? wk : wq;
  float y1 = x1 * rr * wn[2 * l], y2 = x2 * rr * wn[2 * l + 1];
  if (s >= T) {
    float c = cosb[(size_t)(s - T) * 64 + l];
    float sn = sinb[(size_t)(s - T) * 64 + l];
    float o1 = y1 * c - y2 * sn;
    float o2 = y2 * c + y1 * sn;
    y1 = o1; y2 = o2;
  }
  *(unsigned*)(qkv + base) = (unsigned)f2b(y1) | ((unsigned)f2b(y2) << 16);
}

// ---------------- kernel 4: V transpose -> vt[b][h][d][S] ---------------------
__global__ __launch_bounds__(256) void vtrans_kernel(
    const ushort_t* __restrict__ qkv, ushort_t* __restrict__ vt)
{
  __shared__ ushort_t Tl[HD * 73];     // [d][s] padded stride 73 (146B, breaks conflicts)
  const int t = threadIdx.x;
  const int st = blockIdx.x;           // 36 s-tiles of 64
  const int bh = blockIdx.y;           // 48
  const int b = bh / HEADS, h = bh % HEADS;
  const int s0 = st * 64;
  const ushort_t* vsrc = qkv + (size_t)(b * SS) * NN3 + 2 * DD + h * HD;
#pragma unroll
  for (int i = 0; i < 4; ++i) {
    int c = i * 256 + t;
    int s = c >> 4, dc = c & 15;
    uint4 v4 = *(const uint4*)(vsrc + (size_t)(s0 + s) * NN3 + dc * 8);
    union { uint4 v; ushort_t u[8]; } un; un.v = v4;
#pragma unroll
    for (int j = 0; j < 8; ++j) Tl[(dc * 8 + j) * 73 + s] = un.u[j];
  }
  __syncthreads();
  ushort_t* vdst = vt + (size_t)bh * HD * SS;
#pragma unroll
  for (int i = 0; i < 4; ++i) {
    int c = i * 256 + t;
    int d = c >> 3, sc = c & 7;
    union { uint4 v; ushort_t u[8]; } un;
#pragma unroll
    for (int j = 0; j < 8; ++j) un.u[j] = Tl[d * 73 + sc * 8 + j];
    *(uint4*)(vdst + (size_t)d * SS + s0 + sc * 8) = un.v;
  }
}

// ---------------- kernel 5: flash attention ----------------------------------
#define KSTR 136   // Kl row stride (elems) = 272B, 16B-aligned, breaks bank alignment
#define VSTR 72    // Vl row stride = 144B
#define PSTR 72
__global__ __launch_bounds__(256) void attn_kernel(
    const ushort_t* __restrict__ qkv, const ushort_t* __restrict__ vt,
    float* __restrict__ out)
{
  __shared__ ushort_t Kl[64 * KSTR];       // K tile [kv=64][d=128] padded
  __shared__ ushort_t Vl[HD * VSTR];       // Vt tile [d=128][kv=64] padded
  __shared__ ushort_t Pl[4 * 16 * PSTR];   // per-wave P [16][64] padded
  const int t = threadIdx.x;
  const int w = t >> 6, l = t & 63, quad = l >> 4, lq = l & 15;
  const int qt = blockIdx.x, bh = blockIdx.y;
  const int b = bh / HEADS, h = bh % HEADS;
  const int q0 = qt * 64;
  const ushort_t* qb = qkv + (size_t)(b * SS) * NN3 + h * HD;
  const ushort_t* kbp = qb + DD;
  const ushort_t* vb = vt + (size_t)bh * HD * SS;

  // Q fragments in registers: a[j] = Q[m=lq][k=quad*8+j] per 32-wide k-chunk
  bf16x8 aq[4];
  {
    size_t ro = (size_t)(q0 + w * 16 + lq) * NN3;
#pragma unroll
    for (int kc = 0; kc < 4; ++kc) {
      union { uint4 v; bf16x8 b; } un;
      un.v = *(const uint4*)(qb + ro + kc * 32 + quad * 8);
      aq[kc] = un.b;
    }
  }

  f32x4 o[8] = {};
  float mrow[4], lrow[4];
#pragma unroll
  for (int r = 0; r < 4; ++r) { mrow[r] = -3.0e38f; lrow[r] = 0.f; }
  const float scale = 0.088388347648318447f;   // 1/sqrt(128)

  for (int kt = 0; kt < SS / 64; ++kt) {
    const int kv0 = kt * 64;
    __syncthreads();
    // stage K tile [kv][d] (padded rows)
#pragma unroll
    for (int i = 0; i < 4; ++i) {
      int c = i * 256 + t;
      int kv = c >> 4, dc = c & 15;
      *(uint4*)((char*)Kl + kv * 2 * KSTR + dc * 16) =
          *(const uint4*)(kbp + (size_t)(kv0 + kv) * NN3 + dc * 8);
    }
    // stage Vt tile [d][kv] (padded rows)
#pragma unroll
    for (int i = 0; i < 4; ++i) {
      int c = i * 256 + t;
      int d = c >> 3, sc = c & 7;
      *(uint4*)((char*)Vl + d * 2 * VSTR + sc * 16) =
          *(const uint4*)(vb + (size_t)d * SS + kv0 + sc * 8);
    }
    __syncthreads();

    // S = Q K^T : C-layout row=quad*4+r (q), col=lq+nt*16 (kv)
    f32x4 sv[4];
#pragma unroll
    for (int nt = 0; nt < 4; ++nt) {
      f32x4 a = {};
#pragma unroll
      for (int kc = 0; kc < 4; ++kc) {
        bf16x8 bk = *(const bf16x8*)((const char*)Kl + (nt * 16 + lq) * 2 * KSTR + kc * 64 + quad * 16);
        a = __builtin_amdgcn_mfma_f32_16x16x32_bf16(aq[kc], bk, a, 0, 0, 0);
      }
      sv[nt] = a;
    }
    // online softmax (rows live in the 16 lanes of a quad)
    float tmax[4];
#pragma unroll
    for (int r = 0; r < 4; ++r)
      tmax[r] = fmaxf(fmaxf(sv[0][r], sv[1][r]), fmaxf(sv[2][r], sv[3][r])) * scale;
#pragma unroll
    for (int mk = 1; mk < 16; mk <<= 1)
#pragma unroll
      for (int r = 0; r < 4; ++r)
        tmax[r] = fmaxf(tmax[r], __shfl_xor(tmax[r], mk, 64));
    float al[4], rs[4];
#pragma unroll
    for (int r = 0; r < 4; ++r) {
      float mn = fmaxf(mrow[r], tmax[r]);
      al[r] = __expf(mrow[r] - mn);
      mrow[r] = mn;
      rs[r] = 0.f;
    }
    ushort_t pb[4][4];
#pragma unroll
    for (int nt = 0; nt < 4; ++nt)
#pragma unroll
      for (int r = 0; r < 4; ++r) {
        float p = __expf(fmaf(sv[nt][r], scale, -mrow[r]));
        rs[r] += p;
        pb[nt][r] = f2b(p);
      }
#pragma unroll
    for (int mk = 1; mk < 16; mk <<= 1)
#pragma unroll
      for (int r = 0; r < 4; ++r)
        rs[r] += __shfl_xor(rs[r], mk, 64);
#pragma unroll
    for (int r = 0; r < 4; ++r)
      lrow[r] = lrow[r] * al[r] + rs[r];
#pragma unroll
    for (int nt2 = 0; nt2 < 8; ++nt2)
#pragma unroll
      for (int r = 0; r < 4; ++r)
        o[nt2][r] *= al[r];
    // P: C-layout -> LDS -> A-layout (same-wave, DS pipe is in-order)
    ushort_t* pw = Pl + w * 16 * PSTR;
#pragma unroll
    for (int nt = 0; nt < 4; ++nt)
#pragma unroll
      for (int r = 0; r < 4; ++r)
        pw[(quad * 4 + r) * PSTR + nt * 16 + lq] = pb[nt][r];
    // O += P V  (B^T form with Vt[d][kv])
#pragma unroll
    for (int kc2 = 0; kc2 < 2; ++kc2) {
      bf16x8 ap = *(const bf16x8*)((const char*)Pl + (w * 16 + lq) * 2 * PSTR + kc2 * 64 + quad * 16);
#pragma unroll
      for (int nt2 = 0; nt2 < 8; ++nt2) {
        bf16x8 bv = *(const bf16x8*)((const char*)Vl + (nt2 * 16 + lq) * 2 * VSTR + kc2 * 64 + quad * 16);
        o[nt2] = __builtin_amdgcn_mfma_f32_16x16x32_bf16(ap, bv, o[nt2], 0, 0, 0);
      }
    }
  }
  // epilogue: divide by l, store f32
#pragma unroll
  for (int r = 0; r < 4; ++r) {
    float inv = 1.0f / lrow[r];
    size_t rowo = (size_t)(b * SS + q0 + w * 16 + quad * 4 + r) * DD + h * HD;
#pragma unroll
    for (int nt2 = 0; nt2 < 8; ++nt2)
      out[rowo + nt2 * 16 + lq] = o[nt2][r] * inv;
  }
}

// ---------------- launch ------------------------------------------------------
extern "C" void kernel_launch(void* const* d_in, const int* in_sizes, int n_in,
                              void* d_out, int out_size, void* d_ws, size_t ws_size,
                              hipStream_t stream)
{
  const float* hs   = (const float*)d_in[0];
  const float* wqkv = (const float*)d_in[1];
  const float* bq   = (const float*)d_in[2];
  const float* wqn  = (const float*)d_in[3];
  const float* wkn  = (const float*)d_in[4];
  const float* cosb = (const float*)d_in[5];
  const float* sinb = (const float*)d_in[6];
  const int*   tseq = (const int*)d_in[7];
  float* out = (float*)d_out;
  char* ws = (char*)d_ws;

  // ws layout (bytes): [hs_bf16 | w_bf16 | qkv_bf16], vt aliases hs_bf16 (spent after GEMM)
  ushort_t* hsb  = (ushort_t*)ws;                               // 28,311,552 B
  ushort_t* wb   = (ushort_t*)(ws + 28311552);                  // 56,623,104 B
  ushort_t* qkvb = (ushort_t*)(ws + 28311552 + 56623104);       // 84,934,656 B
  ushort_t* vtb  = hsb;                                         // alias, same size

  cvt_bf16_kernel<<<6912, 256, 0, stream>>>(hs, hsb, 1769472);      // 4608*3072/8
  cvt_bf16_kernel<<<13824, 256, 0, stream>>>(wqkv, wb, 3538944);    // 9216*3072/8
  gemm_qkv_kernel<<<dim3(72, 36), 256, 0, stream>>>(hsb, wb, bq, qkvb);
  norm_rope_kernel<<<55296, 256, 0, stream>>>(qkvb, wqn, wkn, cosb, sinb, tseq);
  vtrans_kernel<<<dim3(36, 48), 256, 0, stream>>>(qkvb, vtb);
  attn_kernel<<<dim3(36, 48), 256, 0, stream>>>(qkvb, vtb, out);
}